// Round 1
// baseline (150.932 us; speedup 1.0000x reference)
//
#include <hip/hip_runtime.h>

typedef __attribute__((ext_vector_type(8))) short short8;
typedef __attribute__((ext_vector_type(4))) float f32x4;

__device__ __forceinline__ unsigned short f2bf(float f) {
  unsigned int u = __builtin_bit_cast(unsigned int, f);
  u += 0x7fffu + ((u >> 16) & 1u);
  return (unsigned short)(u >> 16);
}
__device__ __forceinline__ float bf2f(unsigned short s) {
  return __builtin_bit_cast(float, ((unsigned int)s) << 16);
}

// ---------------- prep: f32 -> bf16 casts (token, entity) ----------------
__global__ __launch_bounds__(256) void cast_bf16_kernel(
    const float* __restrict__ a, unsigned short* __restrict__ oa, int na4,
    const float* __restrict__ b, unsigned short* __restrict__ ob, int nb4) {
  int i = blockIdx.x * 256 + threadIdx.x;
  const float* s; unsigned short* d; int q;
  if (i < na4) { s = a; d = oa; q = i; }
  else { q = i - na4; if (q >= nb4) return; s = b; d = ob; }
  float4 v = ((const float4*)s)[q];
  ushort4 o;
  o.x = f2bf(v.x); o.y = f2bf(v.y); o.z = f2bf(v.z); o.w = f2bf(v.w);
  ((ushort4*)d)[q] = o;
}

// ------------- prep: transpose + cast W[k][n] -> WT[n][k] bf16 -------------
__global__ __launch_bounds__(256) void transpose_cast_kernel(
    const float* __restrict__ w0, unsigned short* __restrict__ o0,
    const float* __restrict__ w1, unsigned short* __restrict__ o1) {
  __shared__ float tile[64][65];
  const float* src = blockIdx.z ? w1 : w0;
  unsigned short* dst = blockIdx.z ? o1 : o0;
  int bx = blockIdx.x * 64, by = blockIdx.y * 64;
  int tid = threadIdx.x;
  int r0 = tid >> 4, c0 = (tid & 15) << 2;
#pragma unroll
  for (int p = 0; p < 4; ++p) {
    int r = p * 16 + r0;
    float4 v = *(const float4*)&src[(size_t)(by + r) * 1024 + bx + c0];
    tile[r][c0] = v.x; tile[r][c0 + 1] = v.y; tile[r][c0 + 2] = v.z; tile[r][c0 + 3] = v.w;
  }
  __syncthreads();
#pragma unroll
  for (int p = 0; p < 4; ++p) {
    int r = p * 16 + r0;  // output row n = bx + r
    ushort4 o;
    o.x = f2bf(tile[c0 + 0][r]); o.y = f2bf(tile[c0 + 1][r]);
    o.z = f2bf(tile[c0 + 2][r]); o.w = f2bf(tile[c0 + 3][r]);
    *(ushort4*)&dst[(size_t)(bx + r) * 1024 + by + c0] = o;
  }
}

// ------------- bf16 MFMA GEMM: C[M,1024] = A[M,1024] @ BT^T + bias -------------
// Two problems fused in one launch (token branch mt<mtiles1, entity branch after).
// 128x128 tile, BK=32, 4 waves of 4x4 16x16x32 frags. B given transposed [N][K].
__global__ __launch_bounds__(256) void gemm_bf16_kernel(
    const unsigned short* __restrict__ A1, const unsigned short* __restrict__ BT1,
    const float* __restrict__ bias1, float* __restrict__ C1, int mtiles1, int M1,
    const unsigned short* __restrict__ A2, const unsigned short* __restrict__ BT2,
    const float* __restrict__ bias2, float* __restrict__ C2, int M2) {
  __shared__ __attribute__((aligned(16))) unsigned short As[128][40];  // +8 pad: <=2-way conflicts
  __shared__ __attribute__((aligned(16))) unsigned short Bs[128][40];
  int mt = blockIdx.y;
  const int nt = blockIdx.x;
  const unsigned short *A, *BT; const float* bias; float* C; int M;
  if (mt < mtiles1) { A = A1; BT = BT1; bias = bias1; C = C1; M = M1; }
  else { mt -= mtiles1; A = A2; BT = BT2; bias = bias2; C = C2; M = M2; }
  const int tid = threadIdx.x;
  const int m0 = mt << 7, n0 = nt << 7;
  const int lane = tid & 63;
  const int wm = (tid >> 7) & 1, wn = (tid >> 6) & 1;
  const int l16 = lane & 15, oct = lane >> 4, ko = oct << 3;
  f32x4 acc[4][4] = {};
  for (int kt = 0; kt < 32; ++kt) {
    const int k0 = kt << 5;
    __syncthreads();
#pragma unroll
    for (int p = 0; p < 2; ++p) {
      int ch = p * 256 + tid;
      int r = ch >> 2, co = (ch & 3) << 3;
      int ra = m0 + r; if (ra > M - 1) ra = M - 1;  // clamp for M=64 entity problem
      *(uint4*)&As[r][co] = *(const uint4*)&A[(size_t)ra * 1024 + k0 + co];
      *(uint4*)&Bs[r][co] = *(const uint4*)&BT[(size_t)(n0 + r) * 1024 + k0 + co];
    }
    __syncthreads();
    short8 af[4], bf[4];
#pragma unroll
    for (int i = 0; i < 4; ++i) af[i] = *(const short8*)&As[(wm << 6) + (i << 4) + l16][ko];
#pragma unroll
    for (int j = 0; j < 4; ++j) bf[j] = *(const short8*)&Bs[(wn << 6) + (j << 4) + l16][ko];
#pragma unroll
    for (int i = 0; i < 4; ++i)
#pragma unroll
      for (int j = 0; j < 4; ++j)
        acc[i][j] = __builtin_amdgcn_mfma_f32_16x16x32_bf16(af[i], bf[j], acc[i][j], 0, 0, 0);
  }
  // C/D layout: col = lane&15, row = oct*4 + reg  [m89-verified]
#pragma unroll
  for (int i = 0; i < 4; ++i) {
    int rbase = m0 + (wm << 6) + (i << 4) + (oct << 2);
#pragma unroll
    for (int j = 0; j < 4; ++j) {
      int col = n0 + (wn << 6) + (j << 4) + l16;
      float bv = bias[col];
#pragma unroll
      for (int r = 0; r < 4; ++r) {
        int row = rbase + r;
        if (row < M) C[(size_t)row * 1024 + col] = acc[i][j][r] + bv;
      }
    }
  }
}

// ------------- fusion: cls[b,e,t] = sum_h relu(t+e)*Wp + bp; mask; sigmoid -------------
// WG: 8 t-rows x 16 entities x 2 h-halves = 256 threads, one partial per thread.
__global__ __launch_bounds__(256) void fuse_kernel(
    const float* __restrict__ tws, const float* __restrict__ ews,
    const float* __restrict__ wp, const float* __restrict__ bp,
    const int* __restrict__ mask, float* __restrict__ out) {
  __shared__ __attribute__((aligned(16))) unsigned short eL[16][1028];  // bf16, +4 pad
  __shared__ __attribute__((aligned(16))) float wpL[1024];
  __shared__ float part[128];
  const int tc = blockIdx.x;  // 0..127 (8-row t chunks)
  const int b = blockIdx.y;   // 0..3
  const int tid = threadIdx.x;
  // stage 16 entity rows (f32 -> bf16) + Wp
#pragma unroll
  for (int p = 0; p < 16; ++p) {
    int q = p * 256 + tid;      // float4 index in [0, 4096)
    int er = q >> 8, ec = (q & 255) << 2;
    float4 v = *(const float4*)&ews[((b * 16 + er) << 10) + ec];
    ushort4 o;
    o.x = f2bf(v.x); o.y = f2bf(v.y); o.z = f2bf(v.z); o.w = f2bf(v.w);
    *(ushort4*)&eL[er][ec] = o;
  }
  {
    int c = tid << 2;
    *(float4*)&wpL[c] = *(const float4*)&wp[c];
  }
  __syncthreads();
  const int tl = tid & 7, e = (tid >> 3) & 15, hh = tid >> 7;
  const int t = tc * 8 + tl;
  const float4* tp = (const float4*)&tws[((size_t)((b << 10) + t)) << 10];
  const ushort4* ep = (const ushort4*)&eL[e][0];
  const float4* wq = (const float4*)&wpL[0];
  const int h0 = hh << 7;  // 128 float4-iters per half
  float s0 = 0.f, s1 = 0.f, s2 = 0.f, s3 = 0.f;
#pragma unroll 8
  for (int h = h0; h < h0 + 128; ++h) {
    float4 tv = tp[h];
    ushort4 eu = ep[h];
    float4 wv = wq[h];
    s0 += fmaxf(tv.x + bf2f(eu.x), 0.f) * wv.x;
    s1 += fmaxf(tv.y + bf2f(eu.y), 0.f) * wv.y;
    s2 += fmaxf(tv.z + bf2f(eu.z), 0.f) * wv.z;
    s3 += fmaxf(tv.w + bf2f(eu.w), 0.f) * wv.w;
  }
  float acc = (s0 + s1) + (s2 + s3);
  if (hh) part[tid - 128] = acc;
  __syncthreads();
  if (!hh) {
    float cls = acc + part[tid] + bp[0];
    if (mask[(b << 10) + t] == 0) cls = -10000.0f;
    float pv = 1.0f / (1.0f + __expf(-cls));
    int oidx = ((b * 16 + e) << 10) + t;
    out[oidx] = cls;
    out[65536 + oidx] = pv;
  }
}

extern "C" void kernel_launch(void* const* d_in, const int* in_sizes, int n_in,
                              void* d_out, int out_size, void* d_ws, size_t ws_size,
                              hipStream_t stream) {
  const float* token = (const float*)d_in[0];   // [4,1024,1024]
  const float* entity = (const float*)d_in[1];  // [4,16,1024]
  const int* mask = (const int*)d_in[2];        // [4,1024] (bool as int32 — declared gamble)
  const float* Wt = (const float*)d_in[3];
  const float* bt = (const float*)d_in[4];
  const float* We = (const float*)d_in[5];
  const float* be = (const float*)d_in[6];
  const float* Wp = (const float*)d_in[7];
  const float* bp = (const float*)d_in[8];
  float* out = (float*)d_out;  // [cls 65536][p 65536]

  char* ws = (char*)d_ws;
  float* tws = (float*)ws;                                        // 16 MB  t = token@Wt+bt
  float* ews = (float*)(ws + (16u << 20));                        // 256 KB e = entity@We+be
  unsigned short* tokb = (unsigned short*)(ws + (16u << 20) + (256u << 10));  // 8 MB
  unsigned short* entb = tokb + 4096 * 1024;                      // 128 KB
  unsigned short* WtT = entb + 64 * 1024;                         // 2 MB
  unsigned short* WeT = WtT + 1024 * 1024;                        // 2 MB   (total ~28.4 MB)

  cast_bf16_kernel<<<4160, 256, 0, stream>>>(token, tokb, 1048576, entity, entb, 16384);
  transpose_cast_kernel<<<dim3(16, 16, 2), 256, 0, stream>>>(Wt, WtT, We, WeT);
  gemm_bf16_kernel<<<dim3(8, 33), 256, 0, stream>>>(tokb, WtT, bt, tws, 32, 4096,
                                                    entb, WeT, be, ews, 64);
  fuse_kernel<<<dim3(128, 4), 256, 0, stream>>>(tws, ews, Wp, bp, mask, out);
}

// Round 2
// 134.434 us; speedup vs baseline: 1.1227x; 1.1227x over previous
//
#include <hip/hip_runtime.h>

typedef __attribute__((ext_vector_type(8))) short short8;
typedef __attribute__((ext_vector_type(4))) float f32x4;

__device__ __forceinline__ unsigned short f2bf(float f) {
  unsigned int u = __builtin_bit_cast(unsigned int, f);
  u += 0x7fffu + ((u >> 16) & 1u);
  return (unsigned short)(u >> 16);
}
__device__ __forceinline__ float lo_bf(unsigned int u) {
  return __builtin_bit_cast(float, u << 16);
}
__device__ __forceinline__ float hi_bf(unsigned int u) {
  return __builtin_bit_cast(float, u & 0xffff0000u);
}

// 16B-wide async global->LDS DMA. LDS dest = wave-uniform base + lane*16.
__device__ __forceinline__ void gload_lds16(const void* g, void* l) {
  __builtin_amdgcn_global_load_lds(
      (const __attribute__((address_space(1))) void*)g,
      (__attribute__((address_space(3))) void*)l, 16, 0, 0);
}

// ---- prep: token/entity f32->bf16 cast + W transpose-cast, one launch ----
// blocks 0..4095 token cast, 4096..4159 entity cast, 4160..4671 transposes
__global__ __launch_bounds__(256) void prep_kernel(
    const float* __restrict__ token, unsigned short* __restrict__ tokb,
    const float* __restrict__ entity, unsigned short* __restrict__ entb,
    const float* __restrict__ Wt, unsigned short* __restrict__ WtT,
    const float* __restrict__ We, unsigned short* __restrict__ WeT) {
  __shared__ float tile[64][65];
  const int bid = blockIdx.x, tid = threadIdx.x;
  if (bid < 4160) {
    const float* s; unsigned short* d; int q = bid * 256 + tid;
    if (bid < 4096) { s = token; d = tokb; }
    else { s = entity; d = entb; q -= 4096 * 256; }
    float4 v = ((const float4*)s)[q];
    ushort4 o;
    o.x = f2bf(v.x); o.y = f2bf(v.y); o.z = f2bf(v.z); o.w = f2bf(v.w);
    ((ushort4*)d)[q] = o;
  } else {
    int tb = bid - 4160;                    // 0..511
    const float* src = (tb >> 8) ? We : Wt;
    unsigned short* dst = (tb >> 8) ? WeT : WtT;
    int r8 = tb & 255;
    int bx = (r8 & 15) << 6, by = ((r8 >> 4) & 15) << 6;
    int r0 = tid >> 4, c0 = (tid & 15) << 2;
#pragma unroll
    for (int p = 0; p < 4; ++p) {
      int r = p * 16 + r0;
      float4 v = *(const float4*)&src[(size_t)(by + r) * 1024 + bx + c0];
      tile[r][c0] = v.x; tile[r][c0 + 1] = v.y;
      tile[r][c0 + 2] = v.z; tile[r][c0 + 3] = v.w;
    }
    __syncthreads();
#pragma unroll
    for (int p = 0; p < 4; ++p) {
      int r = p * 16 + r0;
      ushort4 o;
      o.x = f2bf(tile[c0 + 0][r]); o.y = f2bf(tile[c0 + 1][r]);
      o.z = f2bf(tile[c0 + 2][r]); o.w = f2bf(tile[c0 + 3][r]);
      *(ushort4*)&dst[(size_t)(bx + r) * 1024 + by + c0] = o;
    }
  }
}

// ---- GEMM (m97 structure): 128x128 tile, BK=32, global_load_lds staging ----
// grid (8, 65): y<64 token split-K=2 (mt=y>>1, ks=y&1), y==64 entity full-K.
// C partials stored bf16; bias added once (ks==0 / entity).
__global__ __launch_bounds__(256) void gemm_kernel(
    const unsigned short* __restrict__ tokb, const unsigned short* __restrict__ WtT,
    unsigned short* __restrict__ tws0, unsigned short* __restrict__ tws1,
    const unsigned short* __restrict__ entb, const unsigned short* __restrict__ WeT,
    const float* __restrict__ bt, const float* __restrict__ be,
    unsigned short* __restrict__ ews) {
  __shared__ __attribute__((aligned(16))) unsigned short As[128][32];  // unpadded: DMA layout
  __shared__ __attribute__((aligned(16))) unsigned short Bs[128][32];
  const int tid = threadIdx.x;
  const int nt = blockIdx.x, yy = blockIdx.y;
  const unsigned short *A, *BT; const float* bias; unsigned short* C;
  int m0, kbase, niter, M, addbias;
  if (yy < 64) {
    A = tokb; BT = WtT; C = (yy & 1) ? tws1 : tws0; bias = bt;
    m0 = (yy >> 1) << 7; kbase = (yy & 1) << 9; niter = 16; M = 4096;
    addbias = (yy & 1) == 0;
  } else {
    A = entb; BT = WeT; C = ews; bias = be;
    m0 = 0; kbase = 0; niter = 32; M = 64; addbias = 1;
  }
  const int n0 = nt << 7;
  const int lane = tid & 63, w = tid >> 6;
  const int wm = (tid >> 7) & 1, wn = (tid >> 6) & 1;
  const int l16 = lane & 15, oct = lane >> 4, ko = oct << 3;
  // staging: chunk c1 = tid (rows 0..63), c2 = tid+256 (rows 64..127)
  const int arow1 = tid >> 2, arow2 = arow1 + 64;
  const int kc = (tid & 3) << 3;
  int ar1 = m0 + arow1; if (ar1 >= M) ar1 = M - 1;
  int ar2 = m0 + arow2; if (ar2 >= M) ar2 = M - 1;
  const unsigned short* aP1 = A + (size_t)ar1 * 1024 + kbase + kc;
  const unsigned short* aP2 = A + (size_t)ar2 * 1024 + kbase + kc;
  const unsigned short* bP1 = BT + (size_t)(n0 + arow1) * 1024 + kbase + kc;
  const unsigned short* bP2 = BT + (size_t)(n0 + arow2) * 1024 + kbase + kc;
  unsigned short* aL = &As[0][0] + w * 512;   // wave-uniform LDS base (shorts)
  unsigned short* bL = &Bs[0][0] + w * 512;
  f32x4 acc[4][4] = {};
  for (int kt = 0; kt < niter; ++kt) {
    __syncthreads();
    gload_lds16(aP1, aL);
    gload_lds16(aP2, aL + 2048);
    gload_lds16(bP1, bL);
    gload_lds16(bP2, bL + 2048);
    aP1 += 32; aP2 += 32; bP1 += 32; bP2 += 32;
    __syncthreads();
    short8 af[4], bf[4];
#pragma unroll
    for (int i = 0; i < 4; ++i) af[i] = *(const short8*)&As[(wm << 6) + (i << 4) + l16][ko];
#pragma unroll
    for (int j = 0; j < 4; ++j) bf[j] = *(const short8*)&Bs[(wn << 6) + (j << 4) + l16][ko];
#pragma unroll
    for (int i = 0; i < 4; ++i)
#pragma unroll
      for (int j = 0; j < 4; ++j)
        acc[i][j] = __builtin_amdgcn_mfma_f32_16x16x32_bf16(af[i], bf[j], acc[i][j], 0, 0, 0);
  }
  // C/D: col = lane&15, row = oct*4 + reg  [m89]
#pragma unroll
  for (int i = 0; i < 4; ++i) {
    int rbase = (wm << 6) + (i << 4) + (oct << 2);
#pragma unroll
    for (int j = 0; j < 4; ++j) {
      int col = n0 + (wn << 6) + (j << 4) + l16;
      float bv = addbias ? bias[col] : 0.f;
#pragma unroll
      for (int r = 0; r < 4; ++r) {
        int row = rbase + r;
        if (m0 + row < M)
          C[(size_t)(m0 + row) * 1024 + col] = f2bf(acc[i][j][r] + bv);
      }
    }
  }
}

// ---- fuse: cls[b,e,t] = sum_h relu(t0+t1+e)*Wp + bp; mask; sigmoid ----
// 512 threads = 8 waves, one wave per t-row; lanes sweep h coalesced;
// 16 entity rows (bf16) in LDS; 16 register accumulators; shfl-xor reduce.
__global__ __launch_bounds__(512) void fuse_kernel(
    const unsigned short* __restrict__ tws0, const unsigned short* __restrict__ tws1,
    const unsigned short* __restrict__ ews, const float* __restrict__ wp,
    const float* __restrict__ bp, const int* __restrict__ mask,
    float* __restrict__ out) {
  __shared__ __attribute__((aligned(16))) unsigned short eL[16 * 1024];
  __shared__ __attribute__((aligned(16))) float wpL[1024];
  const int tc = blockIdx.x, b = blockIdx.y, tid = threadIdx.x;
  {
    const uint4* src = (const uint4*)(ews + (size_t)b * 16 * 1024);
    uint4* dst = (uint4*)eL;
#pragma unroll
    for (int p = 0; p < 4; ++p) dst[p * 512 + tid] = src[p * 512 + tid];
    if (tid < 256) ((float4*)wpL)[tid] = ((const float4*)wp)[tid];
  }
  __syncthreads();
  const int w = tid >> 6, lane = tid & 63;
  const int t = (tc << 3) + w;
  const size_t rowoff = (size_t)(((b << 10) + t)) << 10;
  const uint4* t0p = (const uint4*)(tws0 + rowoff);
  const uint4* t1p = (const uint4*)(tws1 + rowoff);
  float acc[16];
#pragma unroll
  for (int e = 0; e < 16; ++e) acc[e] = 0.f;
#pragma unroll
  for (int it = 0; it < 2; ++it) {
    const int idx = (it << 6) + lane;  // uint4 index, 128 per row
    uint4 q0 = t0p[idx], q1 = t1p[idx];
    float tv0 = lo_bf(q0.x) + lo_bf(q1.x), tv1 = hi_bf(q0.x) + hi_bf(q1.x);
    float tv2 = lo_bf(q0.y) + lo_bf(q1.y), tv3 = hi_bf(q0.y) + hi_bf(q1.y);
    float tv4 = lo_bf(q0.z) + lo_bf(q1.z), tv5 = hi_bf(q0.z) + hi_bf(q1.z);
    float tv6 = lo_bf(q0.w) + lo_bf(q1.w), tv7 = hi_bf(q0.w) + hi_bf(q1.w);
    float4 wa = *(const float4*)&wpL[idx << 3];
    float4 wb = *(const float4*)&wpL[(idx << 3) + 4];
#pragma unroll
    for (int e = 0; e < 16; ++e) {
      uint4 eu = *(const uint4*)&eL[(e << 10) + (idx << 3)];
      float s = acc[e];
      s = fmaf(fmaxf(tv0 + lo_bf(eu.x), 0.f), wa.x, s);
      s = fmaf(fmaxf(tv1 + hi_bf(eu.x), 0.f), wa.y, s);
      s = fmaf(fmaxf(tv2 + lo_bf(eu.y), 0.f), wa.z, s);
      s = fmaf(fmaxf(tv3 + hi_bf(eu.y), 0.f), wa.w, s);
      s = fmaf(fmaxf(tv4 + lo_bf(eu.z), 0.f), wb.x, s);
      s = fmaf(fmaxf(tv5 + hi_bf(eu.z), 0.f), wb.y, s);
      s = fmaf(fmaxf(tv6 + lo_bf(eu.w), 0.f), wb.z, s);
      s = fmaf(fmaxf(tv7 + hi_bf(eu.w), 0.f), wb.w, s);
      acc[e] = s;
    }
  }
#pragma unroll
  for (int e = 0; e < 16; ++e)
#pragma unroll
    for (int o = 32; o > 0; o >>= 1) acc[e] += __shfl_xor(acc[e], o, 64);
  const int esel = lane & 15;
  float v = acc[0];
#pragma unroll
  for (int e = 1; e < 16; ++e) v = (esel == e) ? acc[e] : v;
  float cls = v + bp[0];
  if (mask[(b << 10) + t] == 0) cls = -10000.0f;
  float pv = 1.0f / (1.0f + __expf(-cls));
  size_t oidx = ((size_t)((b << 4) + esel) << 10) + t;
  if (lane < 16) out[oidx] = cls;
  else if (lane < 32) out[65536 + oidx] = pv;
}

extern "C" void kernel_launch(void* const* d_in, const int* in_sizes, int n_in,
                              void* d_out, int out_size, void* d_ws, size_t ws_size,
                              hipStream_t stream) {
  const float* token = (const float*)d_in[0];
  const float* entity = (const float*)d_in[1];
  const int* mask = (const int*)d_in[2];
  const float* Wt = (const float*)d_in[3];
  const float* bt = (const float*)d_in[4];
  const float* We = (const float*)d_in[5];
  const float* be = (const float*)d_in[6];
  const float* Wp = (const float*)d_in[7];
  const float* bp = (const float*)d_in[8];
  float* out = (float*)d_out;

  char* ws = (char*)d_ws;
  unsigned short* tws0 = (unsigned short*)ws;              // 8 MB  (token partial ks=0, bf16)
  unsigned short* tws1 = tws0 + (size_t)4096 * 1024;       // 8 MB  (ks=1)
  unsigned short* ews  = tws1 + (size_t)4096 * 1024;       // 128 KB (entity out, bf16)
  unsigned short* tokb = ews + 64 * 1024;                  // 8 MB
  unsigned short* entb = tokb + (size_t)4096 * 1024;       // 128 KB
  unsigned short* WtT  = entb + 64 * 1024;                 // 2 MB
  unsigned short* WeT  = WtT + (size_t)1024 * 1024;        // 2 MB  (total ~28.3 MB)

  prep_kernel<<<4672, 256, 0, stream>>>(token, tokb, entity, entb, Wt, WtT, We, WeT);
  gemm_kernel<<<dim3(8, 65), 256, 0, stream>>>(tokb, WtT, tws0, tws1, entb, WeT, bt, be, ews);
  fuse_kernel<<<dim3(128, 4), 512, 0, stream>>>(tws0, tws1, ews, Wp, bp, mask, out);
}